// Round 15
// baseline (107.284 us; speedup 1.0000x reference)
//
#include <hip/hip_runtime.h>
#include <hip/hip_bf16.h>

#define D 128
#define H 256
#define NB 32
#define NN 128

typedef __attribute__((ext_vector_type(8))) short short8;
typedef __attribute__((ext_vector_type(4))) float f32x4;
typedef __attribute__((ext_vector_type(2))) float f32x2;
typedef __attribute__((ext_vector_type(4))) unsigned int uint4v;

__device__ __forceinline__ unsigned short to_bf16u(float f) {
  unsigned u = __builtin_bit_cast(unsigned, f);
  u = (u + 0x7fffu + ((u >> 16) & 1u)) >> 16;
  return (unsigned short)u;
}

// packed f32x2 -> bf16x2 (RNE); v_cvt_pk_bf16_f32
__device__ __forceinline__ unsigned cvt_pk(float lo, float hi) {
  union { __hip_bfloat162_raw h; unsigned u; } c;
  __hip_bfloat162 t = __float22bfloat162_rn(make_float2(lo, hi));
  c.h = *reinterpret_cast<__hip_bfloat162_raw*>(&t);
  return c.u;
}

// v_pk_add_f32 (verified R7-R9). v_pk_add_bf16 does NOT exist on gfx950 (R10).
__device__ __forceinline__ f32x2 pk_add(f32x2 a, f32x2 b) {
  f32x2 d;
  asm("v_pk_add_f32 %0, %1, %2" : "=v"(d) : "v"(a), "v"(b));
  return d;
}

// packed relu on bf16 pair: signed-i16 max with 0 (verified R7-R9)
__device__ __forceinline__ unsigned pk_relu(unsigned x) {
  unsigned d;
  asm("v_pk_max_i16 %0, %1, %2" : "=v"(d) : "v"(x), "v"(0u));
  return d;
}

// ---------------- Kernel 1: LN*mask + mw1 projections; blocks >=512 repack mw2 ----
__global__ __launch_bounds__(512) void k_ln_proj(
    const float* __restrict__ nodes, const float* __restrict__ node_mask,
    const float* __restrict__ ln_g, const float* __restrict__ ln_b,
    const float* __restrict__ mw1, const float* __restrict__ mw2,
    float* __restrict__ xi_p, unsigned short* __restrict__ xjb,
    short* __restrict__ bw2) {
  const int tid = threadIdx.x;
  if (blockIdx.x >= 512) {
    // repack mw2 [H][D] f32 -> bf16 MFMA B-fragment order.
    const int t = (blockIdx.x - 512) * 512 + tid;  // 0..4095
    const int lane = t & 63;
    const int tile = t >> 6;
    const int ks = tile >> 3, nt = tile & 7;
#pragma unroll
    for (int e = 0; e < 8; ++e) {
      int k = ks * 32 + ((lane >> 4) << 3) + e;
      int d = nt * 16 + (lane & 15);
      bw2[(size_t)t * 8 + e] = (short)to_bf16u(mw2[k * D + d]);
    }
    return;
  }
  const int row0 = blockIdx.x * 8;
  __shared__ float xs[8][128];
  __shared__ float part[2][8][256];   // team-1 partials (ai, aj)

  {
    const int r = tid >> 6;           // 0..7, wave = row
    const int c2 = (tid & 63) << 1;
    float2 v = *(const float2*)(nodes + (size_t)(row0 + r) * D + c2);
    float s1 = v.x + v.y;
    float s2 = v.x * v.x + v.y * v.y;
#pragma unroll
    for (int off = 1; off < 64; off <<= 1) {
      s1 += __shfl_xor(s1, off);
      s2 += __shfl_xor(s2, off);
    }
    float mu = s1 * (1.0f / 128.0f);
    float var = s2 * (1.0f / 128.0f) - mu * mu;
    float rsig = rsqrtf(var + 1e-5f);
    float m = node_mask[row0 + r];
    float2 g2 = *(const float2*)(ln_g + c2);
    float2 b2 = *(const float2*)(ln_b + c2);
    xs[r][c2]     = ((v.x - mu) * rsig * g2.x + b2.x) * m;
    xs[r][c2 + 1] = ((v.y - mu) * rsig * g2.y + b2.y) * m;
  }
  __syncthreads();

  const int col = tid & 255, team = tid >> 8, d0 = team * 64;
  float ai[8], aj[8];
#pragma unroll
  for (int rr = 0; rr < 8; ++rr) { ai[rr] = 0.f; aj[rr] = 0.f; }
#pragma unroll 4
  for (int d = d0; d < d0 + 64; ++d) {
    float wi = mw1[d * H + col];
    float wj = mw1[(D + d) * H + col];
#pragma unroll
    for (int rr = 0; rr < 8; ++rr) {
      float xv = xs[rr][d];
      ai[rr] = fmaf(xv, wi, ai[rr]);
      aj[rr] = fmaf(xv, wj, aj[rr]);
    }
  }
  if (team == 1) {
#pragma unroll
    for (int rr = 0; rr < 8; ++rr) {
      part[0][rr][col] = ai[rr];
      part[1][rr][col] = aj[rr];
    }
  }
  __syncthreads();
  if (team == 0) {
#pragma unroll
    for (int rr = 0; rr < 8; ++rr) {
      float a = ai[rr] + part[0][rr][col];
      float c = aj[rr] + part[1][rr][col];
      xi_p[(size_t)(row0 + rr) * H + col] = a;
      xjb[(size_t)(row0 + rr) * H + col] = to_bf16u(c);
    }
  }
}

// ---------------- Kernel 2: msgs GEMM + mask + sum over j -> agg ----------------
// N-HALF SPLIT (R15): block = (i-pair, n-half). Wave w: i = ib+(w>>2),
// j-slab = (w&3)*32 (TM=32, mf=2), NT=64 (nt 0..3) -> acc[2][4] = 32 AGPRs,
// regs ~95 (headroom for load pipelining). B-LDS halves to 32KB -> block LDS
// ~38KB -> 4 blocks/CU = 16 waves/CU (~50% occ; R8 ceiling was 37% at 124/128
// regs, 2x 8-wave blocks). A-build runs twice per i (once per n-half) — paid
// for by 2x occupancy overlap. R12: B stays in LDS. Tripwire: WRITE ~2MB.
__global__ __launch_bounds__(512, 4) void k_msgs(
    const float* __restrict__ xi_p, const unsigned short* __restrict__ xjb,
    const short* __restrict__ bw2g, const float* __restrict__ mb1,
    const float* __restrict__ mb2, const float* __restrict__ node_mask,
    float* __restrict__ agg) {
  const int b = blockIdx.y;
  const int ib = (blockIdx.x >> 1) * 2;  // i-pair base
  const int nh = blockIdx.x & 1;         // n-half: cols [nh*64, nh*64+64)
  const int tid = threadIdx.x;           // 0..511
  const int w = tid >> 6, l = tid & 63;  // 8 waves
  const int iw = w >> 2;                 // 0..1: which i
  const int jbase = (w & 3) * 32;        // which 32-row j-slab
  const int lg = l >> 4, l15 = l & 15;

  __shared__ short bw2s[16384];          // 32 KB: B fragments for this n-half
  __shared__ float cs[2][256];           // xi_p row + mb1 (f32), per i
  __shared__ float mb2s[64], maskS[128];
  __shared__ float waveAgg[8][64];

  {
    // Copy 32 tiles (ks 0..7, nt 0..3): LDS tile tl=ks*4+nt <- global tile
    // tg=ks*8+nh*4+nt. uint4v units: 64 per tile, 2048 total.
    const uint4v* src = (const uint4v*)bw2g;
    uint4v* dst = (uint4v*)bw2s;
#pragma unroll
    for (int c = 0; c < 4; ++c) {
      int u = c * 512 + tid;             // 0..2047
      int tl = u >> 6;
      int gidx = (((tl >> 2) * 8 + nh * 4 + (tl & 3)) << 6) + (u & 63);
      dst[u] = src[gidx];
    }
  }
  {
    int ii = tid >> 8, k = tid & 255;    // 512 threads = 2 x 256
    cs[ii][k] = xi_p[(size_t)(b * NN + ib + ii) * H + k] + mb1[k];
  }
  if (tid < 64) mb2s[tid] = mb2[nh * 64 + tid];
  if (tid < 128) maskS[tid] = node_mask[b * NN + tid];
  __syncthreads();

  const unsigned short* xrow[2];
#pragma unroll
  for (int mf = 0; mf < 2; ++mf)
    xrow[mf] = xjb + (size_t)(b * NN + jbase + mf * 16 + l15) * H;

  f32x4 acc[2][4];
#pragma unroll
  for (int mf = 0; mf < 2; ++mf)
#pragma unroll
    for (int nt = 0; nt < 4; ++nt)
      acc[mf][nt] = (f32x4){0.f, 0.f, 0.f, 0.f};

  const short8* bfrag = (const short8*)bw2s;

#pragma unroll
  for (int ks = 0; ks < 8; ++ks) {
    const int kb = ks * 32 + lg * 8;     // bf16-elem k offset
    f32x2 cc[4];
    {
      f32x4 c0 = *(const f32x4*)(&cs[iw][kb]);
      f32x4 c1 = *(const f32x4*)(&cs[iw][kb + 4]);
      cc[0] = (f32x2){c0.x, c0.y}; cc[1] = (f32x2){c0.z, c0.w};
      cc[2] = (f32x2){c1.x, c1.y}; cc[3] = (f32x2){c1.z, c1.w};
    }
    short8 af[2];
#pragma unroll
    for (int mf = 0; mf < 2; ++mf) {
      uint4v xu = *(const uint4v*)(xrow[mf] + kb);
      uint4v au;
#pragma unroll
      for (int p = 0; p < 4; ++p) {
        f32x2 xf;
        xf[0] = __builtin_bit_cast(float, xu[p] << 16);
        xf[1] = __builtin_bit_cast(float, xu[p] & 0xffff0000u);
        f32x2 s = pk_add(xf, cc[p]);
        au[p] = pk_relu(cvt_pk(s[0], s[1]));
      }
      af[mf] = __builtin_bit_cast(short8, au);
    }
#pragma unroll
    for (int nt = 0; nt < 4; ++nt) {
      short8 bf = bfrag[(ks * 4 + nt) * 64 + l];
#pragma unroll
      for (int mf = 0; mf < 2; ++mf)
        acc[mf][nt] = __builtin_amdgcn_mfma_f32_16x16x32_bf16(af[mf], bf, acc[mf][nt], 0, 0, 0);
    }
  }

  // Epilogue: relu(acc+mb2)*mask_j, column-sum over the wave's 32 rows.
#pragma unroll
  for (int nt = 0; nt < 4; ++nt) {
    const float bias = mb2s[nt * 16 + l15];
    float s = 0.f;
#pragma unroll
    for (int mf = 0; mf < 2; ++mf) {
      const int jb = jbase + mf * 16 + lg * 4;
#pragma unroll
      for (int r = 0; r < 4; ++r)
        s = fmaf(fmaxf(acc[mf][nt][r] + bias, 0.f), maskS[jb + r], s);
    }
    s += __shfl_xor(s, 16);
    s += __shfl_xor(s, 32);
    if (l < 16) waveAgg[w][nt * 16 + l15] = s;
  }
  __syncthreads();
  if (tid < 128) {
    const int ii = tid >> 6, c6 = tid & 63;  // 2 i's x 64 cols
    agg[(size_t)(b * NN + ib + ii) * D + nh * 64 + c6] =
        waveAgg[ii * 4][c6] + waveAgg[ii * 4 + 1][c6] +
        waveAgg[ii * 4 + 2][c6] + waveAgg[ii * 4 + 3][c6];
  }
}

// ---------------- Kernel 3: update MLP + residual + mask (R8 version) ----------
__global__ __launch_bounds__(512) void k_upd(
    const float* __restrict__ nodes, const float* __restrict__ agg,
    const float* __restrict__ uw1, const float* __restrict__ ub1,
    const float* __restrict__ uw2, const float* __restrict__ ub2,
    const float* __restrict__ node_mask, float* __restrict__ out) {
  const int row0 = blockIdx.x * 8;
  const int tid = threadIdx.x;
  __shared__ float ns[8][128];
  __shared__ float as2[8][128];
  __shared__ float us[8][256];
  __shared__ float pus[8][256];
  {
    const int r = tid >> 6;
    const int c2 = (tid & 63) << 1;
    *(float2*)(&ns[r][c2]) = *(const float2*)(nodes + (size_t)(row0 + r) * D + c2);
    *(float2*)(&as2[r][c2]) = *(const float2*)(agg + (size_t)(row0 + r) * D + c2);
  }
  __syncthreads();

  const int col = tid & 255, team = tid >> 8, d0 = team * 64;
  float acc8[8];
#pragma unroll
  for (int rr = 0; rr < 8; ++rr) acc8[rr] = 0.f;
#pragma unroll 4
  for (int d = d0; d < d0 + 64; ++d) {
    float wa = uw1[d * H + col];
    float wb = uw1[(D + d) * H + col];
#pragma unroll
    for (int rr = 0; rr < 8; ++rr) {
      acc8[rr] = fmaf(ns[rr][d], wa, acc8[rr]);
      acc8[rr] = fmaf(as2[rr][d], wb, acc8[rr]);
    }
  }
  if (team == 1) {
#pragma unroll
    for (int rr = 0; rr < 8; ++rr) pus[rr][col] = acc8[rr];
  }
  __syncthreads();
  if (team == 0) {
    float bias = ub1[col];
#pragma unroll
    for (int rr = 0; rr < 8; ++rr)
      us[rr][col] = fmaxf(acc8[rr] + pus[rr][col] + bias, 0.f);
  }
  __syncthreads();

  const int colD = tid & 127, rg = tid >> 7;  // rows rg and rg+4
  float o0 = 0.f, o1 = 0.f;
#pragma unroll 8
  for (int h = 0; h < 256; ++h) {
    float wv = uw2[h * D + colD];
    o0 = fmaf(us[rg][h], wv, o0);
    o1 = fmaf(us[rg + 4][h], wv, o1);
  }
  const float ub2v = ub2[colD];
  out[(size_t)(row0 + rg) * D + colD] =
      (ns[rg][colD] + o0 + ub2v) * node_mask[row0 + rg];
  out[(size_t)(row0 + rg + 4) * D + colD] =
      (ns[rg + 4][colD] + o1 + ub2v) * node_mask[row0 + rg + 4];
}

extern "C" void kernel_launch(void* const* d_in, const int* in_sizes, int n_in,
                              void* d_out, int out_size, void* d_ws, size_t ws_size,
                              hipStream_t stream) {
  (void)in_sizes; (void)n_in; (void)out_size; (void)ws_size;
  const float* nodes     = (const float*)d_in[0];
  const float* node_mask = (const float*)d_in[1];
  const float* ln_g      = (const float*)d_in[2];
  const float* ln_b      = (const float*)d_in[3];
  const float* mw1       = (const float*)d_in[4];
  const float* mb1       = (const float*)d_in[5];
  const float* mw2       = (const float*)d_in[6];
  const float* mb2       = (const float*)d_in[7];
  const float* uw1       = (const float*)d_in[8];
  const float* ub1       = (const float*)d_in[9];
  const float* uw2       = (const float*)d_in[10];
  const float* ub2       = (const float*)d_in[11];
  float* out = (float*)d_out;

  char* ws = (char*)d_ws;
  float*          xi_p = (float*)(ws);                              // 4 MB
  unsigned short* xjb  = (unsigned short*)(ws + ((size_t)4 << 20)); // 2 MB
  float*          agg  = (float*)(ws + ((size_t)6 << 20));          // 2 MB
  short*          bw2  = (short*)(ws + ((size_t)8 << 20));          // 64 KB

  k_ln_proj<<<520, 512, 0, stream>>>(nodes, node_mask, ln_g, ln_b, mw1, mw2,
                                     xi_p, xjb, bw2);
  k_msgs<<<dim3(NN, NB), 512, 0, stream>>>(xi_p, xjb, bw2, mb1, mb2, node_mask, agg);
  k_upd<<<512, 512, 0, stream>>>(nodes, agg, uw1, ub1, uw2, ub2, node_mask, out);
}

// Round 17
// 87.828 us; speedup vs baseline: 1.2215x; 1.2215x over previous
//
#include <hip/hip_runtime.h>
#include <hip/hip_bf16.h>

#define D 128
#define H 256
#define NB 32
#define NN 128

typedef __attribute__((ext_vector_type(8))) _Float16 f16x8;
typedef __attribute__((ext_vector_type(4))) float f32x4;
typedef __attribute__((ext_vector_type(4))) unsigned int uint4v;

__device__ __forceinline__ unsigned short to_f16u(float f) {
  _Float16 h = (_Float16)f;
  return __builtin_bit_cast(unsigned short, h);
}

// packed f32x2 -> f16x2 (RTZ pack, gfx9+): v_cvt_pkrtz_f16_f32
__device__ __forceinline__ unsigned cvt_pk_f16(float lo, float hi) {
  unsigned d;
  asm("v_cvt_pkrtz_f16_f32 %0, %1, %2" : "=v"(d) : "v"(lo), "v"(hi));
  return d;
}

// packed f16 add: v_pk_add_f16 (VOP3P, gfx9+; NOTE v_pk_add_bf16 does NOT exist - R10)
__device__ __forceinline__ unsigned pk_add_f16(unsigned a, unsigned b) {
  unsigned d;
  asm("v_pk_add_f16 %0, %1, %2" : "=v"(d) : "v"(a), "v"(b));
  return d;
}

// packed relu on f16 pair: signed-i16 max with 0 (sign-bit trick, verified R7-R9)
__device__ __forceinline__ unsigned pk_relu(unsigned x) {
  unsigned d;
  asm("v_pk_max_i16 %0, %1, %2" : "=v"(d) : "v"(x), "v"(0u));
  return d;
}

// ---------------- Kernel 1: LN*mask + mw1 projections; blocks >=512 repack mw2 ----
__global__ __launch_bounds__(512) void k_ln_proj(
    const float* __restrict__ nodes, const float* __restrict__ node_mask,
    const float* __restrict__ ln_g, const float* __restrict__ ln_b,
    const float* __restrict__ mw1, const float* __restrict__ mw2,
    float* __restrict__ xi_p, unsigned short* __restrict__ xjh,
    unsigned short* __restrict__ bw2) {
  const int tid = threadIdx.x;
  if (blockIdx.x >= 512) {
    // repack mw2 [H][D] f32 -> f16 MFMA B-fragment order.
    const int t = (blockIdx.x - 512) * 512 + tid;  // 0..4095
    const int lane = t & 63;
    const int tile = t >> 6;
    const int ks = tile >> 3, nt = tile & 7;
#pragma unroll
    for (int e = 0; e < 8; ++e) {
      int k = ks * 32 + ((lane >> 4) << 3) + e;
      int d = nt * 16 + (lane & 15);
      bw2[(size_t)t * 8 + e] = to_f16u(mw2[k * D + d]);
    }
    return;
  }
  const int row0 = blockIdx.x * 8;
  __shared__ float xs[8][128];
  __shared__ float part[2][8][256];   // team-1 partials (ai, aj)

  {
    const int r = tid >> 6;           // 0..7, wave = row
    const int c2 = (tid & 63) << 1;
    float2 v = *(const float2*)(nodes + (size_t)(row0 + r) * D + c2);
    float s1 = v.x + v.y;
    float s2 = v.x * v.x + v.y * v.y;
#pragma unroll
    for (int off = 1; off < 64; off <<= 1) {
      s1 += __shfl_xor(s1, off);
      s2 += __shfl_xor(s2, off);
    }
    float mu = s1 * (1.0f / 128.0f);
    float var = s2 * (1.0f / 128.0f) - mu * mu;
    float rsig = rsqrtf(var + 1e-5f);
    float m = node_mask[row0 + r];
    float2 g2 = *(const float2*)(ln_g + c2);
    float2 b2 = *(const float2*)(ln_b + c2);
    xs[r][c2]     = ((v.x - mu) * rsig * g2.x + b2.x) * m;
    xs[r][c2 + 1] = ((v.y - mu) * rsig * g2.y + b2.y) * m;
  }
  __syncthreads();

  const int col = tid & 255, team = tid >> 8, d0 = team * 64;
  float ai[8], aj[8];
#pragma unroll
  for (int rr = 0; rr < 8; ++rr) { ai[rr] = 0.f; aj[rr] = 0.f; }
#pragma unroll 4
  for (int d = d0; d < d0 + 64; ++d) {
    float wi = mw1[d * H + col];
    float wj = mw1[(D + d) * H + col];
#pragma unroll
    for (int rr = 0; rr < 8; ++rr) {
      float xv = xs[rr][d];
      ai[rr] = fmaf(xv, wi, ai[rr]);
      aj[rr] = fmaf(xv, wj, aj[rr]);
    }
  }
  if (team == 1) {
#pragma unroll
    for (int rr = 0; rr < 8; ++rr) {
      part[0][rr][col] = ai[rr];
      part[1][rr][col] = aj[rr];
    }
  }
  __syncthreads();
  if (team == 0) {
#pragma unroll
    for (int rr = 0; rr < 8; ++rr) {
      float a = ai[rr] + part[0][rr][col];
      float c = aj[rr] + part[1][rr][col];
      xi_p[(size_t)(row0 + rr) * H + col] = a;
      xjh[(size_t)(row0 + rr) * H + col] = to_f16u(c);
    }
  }
}

// ---------------- Kernel 2: msgs GEMM + mask + sum over j -> agg ----------------
// R8-proven tile (TM=32, NT=128, mf=2, acc[2][8]=64 AGPR, B in LDS, full
// unroll) in FP16 (R17 = R16 with the LDS size bug fixed: bw2s must hold
// 4096 fragments x 16B = 64KB = 32768 shorts; R16's 16384 overran into cs2).
// A-build per dword: v_pk_add_f16 + v_pk_max_i16 = 2 VALU (was 5).
// MFMA: f32_16x16x32_f16 (same layout/rate). Lessons kept: no bigger tiles
// (R4/R7/R9/R11), B in LDS (R12), no rotation (R13), no dup A-build (R15).
// Tripwire: WRITE ~2MB.
__global__ __launch_bounds__(512, 4) void k_msgs(
    const float* __restrict__ xi_p, const unsigned short* __restrict__ xjh,
    const unsigned short* __restrict__ bw2g, const float* __restrict__ mb1,
    const float* __restrict__ mb2, const float* __restrict__ node_mask,
    float* __restrict__ agg) {
  const int b = blockIdx.y;
  const int i0 = blockIdx.x * 2;
  const int tid = threadIdx.x;           // 0..511
  const int w = tid >> 6, l = tid & 63;  // 8 waves
  const int iw = w >> 2;                 // 0..1: which i
  const int jbase = (w & 3) * 32;        // which 32-row j-slab
  const int lg = l >> 4, l15 = l & 15;

  __shared__ unsigned short bw2s[32768]; // 64 KB B fragments (4096 x 16B)
  __shared__ unsigned cs2[2][128];       // f16-pair (xi_p + mb1), per i
  __shared__ float mb2s[128], maskS[128];
  __shared__ float waveAgg[8][128];

  {
    const uint4v* src = (const uint4v*)bw2g;
    uint4v* dst = (uint4v*)bw2s;
#pragma unroll
    for (int c = 0; c < 8; ++c) dst[c * 512 + tid] = src[c * 512 + tid];
  }
  if (tid < 256) {
    int ii = tid >> 7, p = tid & 127;
    float2 xi2 = *(const float2*)(xi_p + (size_t)(b * NN + i0 + ii) * H + 2 * p);
    float2 mbv = *(const float2*)(mb1 + 2 * p);
    cs2[ii][p] = cvt_pk_f16(xi2.x + mbv.x, xi2.y + mbv.y);
  }
  if (tid < 128) { mb2s[tid] = mb2[tid]; maskS[tid] = node_mask[b * NN + tid]; }
  __syncthreads();

  const unsigned short* xrow[2];
#pragma unroll
  for (int mf = 0; mf < 2; ++mf)
    xrow[mf] = xjh + (size_t)(b * NN + jbase + mf * 16 + l15) * H;

  f32x4 acc[2][8];
#pragma unroll
  for (int mf = 0; mf < 2; ++mf)
#pragma unroll
    for (int nt = 0; nt < 8; ++nt)
      acc[mf][nt] = (f32x4){0.f, 0.f, 0.f, 0.f};

  const uint4v* bfrag = (const uint4v*)bw2s;

#pragma unroll
  for (int ks = 0; ks < 8; ++ks) {
    const int kb = ks * 32 + lg * 8;     // f16-elem k offset
    uint4v cc2 = *(const uint4v*)(&cs2[iw][kb >> 1]);
    f16x8 af[2];
#pragma unroll
    for (int mf = 0; mf < 2; ++mf) {
      uint4v xu = *(const uint4v*)(xrow[mf] + kb);
      uint4v au;
#pragma unroll
      for (int p = 0; p < 4; ++p)
        au[p] = pk_relu(pk_add_f16(xu[p], cc2[p]));
      af[mf] = __builtin_bit_cast(f16x8, au);
    }
#pragma unroll
    for (int nt = 0; nt < 8; ++nt) {
      f16x8 bf = __builtin_bit_cast(f16x8, bfrag[(ks * 8 + nt) * 64 + l]);
#pragma unroll
      for (int mf = 0; mf < 2; ++mf)
        acc[mf][nt] = __builtin_amdgcn_mfma_f32_16x16x32_f16(af[mf], bf, acc[mf][nt], 0, 0, 0);
    }
  }

  // Epilogue: relu(acc+mb2)*mask_j, column-sum over the wave's 32 rows.
#pragma unroll
  for (int nt = 0; nt < 8; ++nt) {
    const float bias = mb2s[nt * 16 + l15];
    float s = 0.f;
#pragma unroll
    for (int mf = 0; mf < 2; ++mf) {
      const int jb = jbase + mf * 16 + lg * 4;
#pragma unroll
      for (int r = 0; r < 4; ++r)
        s = fmaf(fmaxf(acc[mf][nt][r] + bias, 0.f), maskS[jb + r], s);
    }
    s += __shfl_xor(s, 16);
    s += __shfl_xor(s, 32);
    if (l < 16) waveAgg[w][nt * 16 + l15] = s;
  }
  __syncthreads();
  if (tid < 256) {
    const int ii = tid >> 7, col = tid & 127;  // 2 i's x 128 cols
    agg[(size_t)(b * NN + i0 + ii) * D + col] =
        waveAgg[ii * 4][col] + waveAgg[ii * 4 + 1][col] +
        waveAgg[ii * 4 + 2][col] + waveAgg[ii * 4 + 3][col];
  }
}

// ---------------- Kernel 3: update MLP + residual + mask (R8 version) ----------
__global__ __launch_bounds__(512) void k_upd(
    const float* __restrict__ nodes, const float* __restrict__ agg,
    const float* __restrict__ uw1, const float* __restrict__ ub1,
    const float* __restrict__ uw2, const float* __restrict__ ub2,
    const float* __restrict__ node_mask, float* __restrict__ out) {
  const int row0 = blockIdx.x * 8;
  const int tid = threadIdx.x;
  __shared__ float ns[8][128];
  __shared__ float as2[8][128];
  __shared__ float us[8][256];
  __shared__ float pus[8][256];
  {
    const int r = tid >> 6;
    const int c2 = (tid & 63) << 1;
    *(float2*)(&ns[r][c2]) = *(const float2*)(nodes + (size_t)(row0 + r) * D + c2);
    *(float2*)(&as2[r][c2]) = *(const float2*)(agg + (size_t)(row0 + r) * D + c2);
  }
  __syncthreads();

  const int col = tid & 255, team = tid >> 8, d0 = team * 64;
  float acc8[8];
#pragma unroll
  for (int rr = 0; rr < 8; ++rr) acc8[rr] = 0.f;
#pragma unroll 4
  for (int d = d0; d < d0 + 64; ++d) {
    float wa = uw1[d * H + col];
    float wb = uw1[(D + d) * H + col];
#pragma unroll
    for (int rr = 0; rr < 8; ++rr) {
      acc8[rr] = fmaf(ns[rr][d], wa, acc8[rr]);
      acc8[rr] = fmaf(as2[rr][d], wb, acc8[rr]);
    }
  }
  if (team == 1) {
#pragma unroll
    for (int rr = 0; rr < 8; ++rr) pus[rr][col] = acc8[rr];
  }
  __syncthreads();
  if (team == 0) {
    float bias = ub1[col];
#pragma unroll
    for (int rr = 0; rr < 8; ++rr)
      us[rr][col] = fmaxf(acc8[rr] + pus[rr][col] + bias, 0.f);
  }
  __syncthreads();

  const int colD = tid & 127, rg = tid >> 7;  // rows rg and rg+4
  float o0 = 0.f, o1 = 0.f;
#pragma unroll 8
  for (int h = 0; h < 256; ++h) {
    float wv = uw2[h * D + colD];
    o0 = fmaf(us[rg][h], wv, o0);
    o1 = fmaf(us[rg + 4][h], wv, o1);
  }
  const float ub2v = ub2[colD];
  out[(size_t)(row0 + rg) * D + colD] =
      (ns[rg][colD] + o0 + ub2v) * node_mask[row0 + rg];
  out[(size_t)(row0 + rg + 4) * D + colD] =
      (ns[rg + 4][colD] + o1 + ub2v) * node_mask[row0 + rg + 4];
}

extern "C" void kernel_launch(void* const* d_in, const int* in_sizes, int n_in,
                              void* d_out, int out_size, void* d_ws, size_t ws_size,
                              hipStream_t stream) {
  (void)in_sizes; (void)n_in; (void)out_size; (void)ws_size;
  const float* nodes     = (const float*)d_in[0];
  const float* node_mask = (const float*)d_in[1];
  const float* ln_g      = (const float*)d_in[2];
  const float* ln_b      = (const float*)d_in[3];
  const float* mw1       = (const float*)d_in[4];
  const float* mb1       = (const float*)d_in[5];
  const float* mw2       = (const float*)d_in[6];
  const float* mb2       = (const float*)d_in[7];
  const float* uw1       = (const float*)d_in[8];
  const float* ub1       = (const float*)d_in[9];
  const float* uw2       = (const float*)d_in[10];
  const float* ub2       = (const float*)d_in[11];
  float* out = (float*)d_out;

  char* ws = (char*)d_ws;
  float*          xi_p = (float*)(ws);                               // 4 MB
  unsigned short* xjh  = (unsigned short*)(ws + ((size_t)4 << 20));  // 2 MB
  float*          agg  = (float*)(ws + ((size_t)6 << 20));           // 2 MB
  unsigned short* bw2  = (unsigned short*)(ws + ((size_t)8 << 20));  // 64 KB

  k_ln_proj<<<520, 512, 0, stream>>>(nodes, node_mask, ln_g, ln_b, mw1, mw2,
                                     xi_p, xjh, bw2);
  k_msgs<<<dim3(NN / 2, NB), 512, 0, stream>>>(xi_p, xjh, bw2, mb1, mb2, node_mask, agg);
  k_upd<<<512, 512, 0, stream>>>(nodes, agg, uw1, ub1, uw2, ub2, node_mask, out);
}

// Round 18
// 70.625 us; speedup vs baseline: 1.5191x; 1.2436x over previous
//
#include <hip/hip_runtime.h>
#include <hip/hip_bf16.h>

#define D 128
#define H 256
#define NB 32
#define NN 128

typedef __attribute__((ext_vector_type(8))) _Float16 f16x8;
typedef __attribute__((ext_vector_type(4))) float f32x4;
typedef __attribute__((ext_vector_type(4))) unsigned int uint4v;

__device__ __forceinline__ unsigned short to_f16u(float f) {
  _Float16 h = (_Float16)f;
  return __builtin_bit_cast(unsigned short, h);
}

// packed f32x2 -> f16x2: v_cvt_pkrtz_f16_f32 (verified R17)
__device__ __forceinline__ unsigned cvt_pk_f16(float lo, float hi) {
  unsigned d;
  asm("v_cvt_pkrtz_f16_f32 %0, %1, %2" : "=v"(d) : "v"(lo), "v"(hi));
  return d;
}

// packed f16 add (verified R17); v_pk_add_bf16 does NOT exist (R10)
__device__ __forceinline__ unsigned pk_add_f16(unsigned a, unsigned b) {
  unsigned d;
  asm("v_pk_add_f16 %0, %1, %2" : "=v"(d) : "v"(a), "v"(b));
  return d;
}

// packed relu: signed-i16 max with 0 (verified R7-R17)
__device__ __forceinline__ unsigned pk_relu(unsigned x) {
  unsigned d;
  asm("v_pk_max_i16 %0, %1, %2" : "=v"(d) : "v"(x), "v"(0u));
  return d;
}

// ---------------- Kernel 0: repack all weights to f16 MFMA B-fragment order ----
// Fragment tile: lane l, elem e holds W[k = ks*32+(l>>4)*8+e][col = nt*16+(l&15)]
// Tile map: 0..127 w1f (mw1, K=128, N=512: ks=t>>5, ntg=t&31)
//           128..255 w3f (uw1, K=256, N=256: ks>>4, &15)
//           256..319 w4f (uw2, K=256, N=128: ks>>3, &7)
//           320..383 bw2 (mw2, K=256, N=128)
__global__ __launch_bounds__(512) void k_repack(
    const float* __restrict__ mw1, const float* __restrict__ uw1,
    const float* __restrict__ uw2, const float* __restrict__ mw2,
    unsigned short* __restrict__ w1f, unsigned short* __restrict__ w3f,
    unsigned short* __restrict__ w4f, unsigned short* __restrict__ bw2) {
  const int gt = blockIdx.x * 512 + threadIdx.x;
  const int tile = gt >> 6, l = gt & 63;
  const int lg = l >> 4, l15 = l & 15;
  if (tile < 128) {
    const int ks = tile >> 5, ntg = tile & 31;
#pragma unroll
    for (int e = 0; e < 8; ++e) {
      int k = ks * 32 + lg * 8 + e;
      int col = ntg * 16 + l15;
      float v = (col < 256) ? mw1[k * 256 + col] : mw1[(128 + k) * 256 + (col - 256)];
      w1f[(size_t)(tile * 64 + l) * 8 + e] = to_f16u(v);
    }
  } else if (tile < 256) {
    const int t = tile - 128, ks = t >> 4, ntg = t & 15;
#pragma unroll
    for (int e = 0; e < 8; ++e) {
      int k = ks * 32 + lg * 8 + e;
      w3f[(size_t)(t * 64 + l) * 8 + e] = to_f16u(uw1[k * 256 + ntg * 16 + l15]);
    }
  } else if (tile < 320) {
    const int t = tile - 256, ks = t >> 3, ntg = t & 7;
#pragma unroll
    for (int e = 0; e < 8; ++e) {
      int k = ks * 32 + lg * 8 + e;
      w4f[(size_t)(t * 64 + l) * 8 + e] = to_f16u(uw2[k * 128 + ntg * 16 + l15]);
    }
  } else {
    const int t = tile - 320, ks = t >> 3, ntg = t & 7;
#pragma unroll
    for (int e = 0; e < 8; ++e) {
      int k = ks * 32 + lg * 8 + e;
      bw2[(size_t)(t * 64 + l) * 8 + e] = to_f16u(mw2[k * 128 + ntg * 16 + l15]);
    }
  }
}

// ---------------- Kernel 1: LN*mask -> f16 + projection GEMM via MFMA ----------
// Block: 16 rows x 256 cols (half = blockIdx.y: 0 -> xi_p f32, 1 -> xjh f16).
// 256 thr / 4 waves; wave w: 16 rows x 64 cols (nt 0..3), K=128 (ks 0..3).
// A from LDS xh (XOR-swizzled 16B groups: [16][256B-stride] rows collide on
// bank 0 otherwise, G4). B-frags (w1f) from global L2 (~500 waves re-read
// 128KB total - trivial, unlike R12's 16k waves).
__global__ __launch_bounds__(256) void k_ln_proj(
    const float* __restrict__ nodes, const float* __restrict__ node_mask,
    const float* __restrict__ ln_g, const float* __restrict__ ln_b,
    const unsigned short* __restrict__ w1f,
    float* __restrict__ xi_p, unsigned short* __restrict__ xjh) {
  const int row0 = blockIdx.x * 16;
  const int half = blockIdx.y;
  const int tid = threadIdx.x;
  __shared__ unsigned short xh[16 * 128];   // f16, 16B-group swizzled

  {
    const int r = tid >> 4, l16 = tid & 15, d0 = l16 * 8;
    float4 v0 = *(const float4*)(nodes + (size_t)(row0 + r) * D + d0);
    float4 v1 = *(const float4*)(nodes + (size_t)(row0 + r) * D + d0 + 4);
    float s1 = v0.x + v0.y + v0.z + v0.w + v1.x + v1.y + v1.z + v1.w;
    float s2 = v0.x * v0.x + v0.y * v0.y + v0.z * v0.z + v0.w * v0.w +
               v1.x * v1.x + v1.y * v1.y + v1.z * v1.z + v1.w * v1.w;
#pragma unroll
    for (int off = 1; off < 16; off <<= 1) {
      s1 += __shfl_xor(s1, off);
      s2 += __shfl_xor(s2, off);
    }
    float mu = s1 * (1.0f / 128.0f);
    float var = s2 * (1.0f / 128.0f) - mu * mu;
    float rsig = rsqrtf(var + 1e-5f);
    float m = node_mask[row0 + r];
    float4 g0 = *(const float4*)(ln_g + d0), g1 = *(const float4*)(ln_g + d0 + 4);
    float4 b0 = *(const float4*)(ln_b + d0), b1 = *(const float4*)(ln_b + d0 + 4);
    float x0 = ((v0.x - mu) * rsig * g0.x + b0.x) * m;
    float x1 = ((v0.y - mu) * rsig * g0.y + b0.y) * m;
    float x2 = ((v0.z - mu) * rsig * g0.z + b0.z) * m;
    float x3 = ((v0.w - mu) * rsig * g0.w + b0.w) * m;
    float x4 = ((v1.x - mu) * rsig * g1.x + b1.x) * m;
    float x5 = ((v1.y - mu) * rsig * g1.y + b1.y) * m;
    float x6 = ((v1.z - mu) * rsig * g1.z + b1.z) * m;
    float x7 = ((v1.w - mu) * rsig * g1.w + b1.w) * m;
    uint4v u;
    u[0] = cvt_pk_f16(x0, x1); u[1] = cvt_pk_f16(x2, x3);
    u[2] = cvt_pk_f16(x4, x5); u[3] = cvt_pk_f16(x6, x7);
    const int g = l16 ^ (r & 7);          // swizzled 16B-group index
    *(uint4v*)(&xh[r * 128 + g * 8]) = u;
  }
  __syncthreads();

  const int w = tid >> 6, l = tid & 63;
  const int lg = l >> 4, l15 = l & 15;
  f32x4 acc[4];
#pragma unroll
  for (int nt = 0; nt < 4; ++nt) acc[nt] = (f32x4){0.f, 0.f, 0.f, 0.f};

#pragma unroll
  for (int ks = 0; ks < 4; ++ks) {
    const int g = (ks * 4 + lg) ^ (l15 & 7);
    f16x8 a = *(const f16x8*)(&xh[l15 * 128 + g * 8]);
#pragma unroll
    for (int nt = 0; nt < 4; ++nt) {
      const int tile = ks * 32 + half * 16 + w * 4 + nt;
      f16x8 bf = *(const f16x8*)(w1f + (size_t)(tile * 64 + l) * 8);
      acc[nt] = __builtin_amdgcn_mfma_f32_16x16x32_f16(a, bf, acc[nt], 0, 0, 0);
    }
  }

  if (half == 0) {
#pragma unroll
    for (int nt = 0; nt < 4; ++nt)
#pragma unroll
      for (int r = 0; r < 4; ++r)
        xi_p[(size_t)(row0 + lg * 4 + r) * H + w * 64 + nt * 16 + l15] = acc[nt][r];
  } else {
#pragma unroll
    for (int nt = 0; nt < 4; ++nt)
#pragma unroll
      for (int r = 0; r < 4; ++r)
        xjh[(size_t)(row0 + lg * 4 + r) * H + w * 64 + nt * 16 + l15] = to_f16u(acc[nt][r]);
  }
}

// ---------------- Kernel 2: msgs GEMM + mask + sum over j -> agg (R17, verbatim) --
__global__ __launch_bounds__(512, 4) void k_msgs(
    const float* __restrict__ xi_p, const unsigned short* __restrict__ xjh,
    const unsigned short* __restrict__ bw2g, const float* __restrict__ mb1,
    const float* __restrict__ mb2, const float* __restrict__ node_mask,
    float* __restrict__ agg) {
  const int b = blockIdx.y;
  const int i0 = blockIdx.x * 2;
  const int tid = threadIdx.x;           // 0..511
  const int w = tid >> 6, l = tid & 63;  // 8 waves
  const int iw = w >> 2;                 // 0..1: which i
  const int jbase = (w & 3) * 32;        // which 32-row j-slab
  const int lg = l >> 4, l15 = l & 15;

  __shared__ unsigned short bw2s[32768]; // 64 KB B fragments (4096 x 16B)
  __shared__ unsigned cs2[2][128];       // f16-pair (xi_p + mb1), per i
  __shared__ float mb2s[128], maskS[128];
  __shared__ float waveAgg[8][128];

  {
    const uint4v* src = (const uint4v*)bw2g;
    uint4v* dst = (uint4v*)bw2s;
#pragma unroll
    for (int c = 0; c < 8; ++c) dst[c * 512 + tid] = src[c * 512 + tid];
  }
  if (tid < 256) {
    int ii = tid >> 7, p = tid & 127;
    float2 xi2 = *(const float2*)(xi_p + (size_t)(b * NN + i0 + ii) * H + 2 * p);
    float2 mbv = *(const float2*)(mb1 + 2 * p);
    cs2[ii][p] = cvt_pk_f16(xi2.x + mbv.x, xi2.y + mbv.y);
  }
  if (tid < 128) { mb2s[tid] = mb2[tid]; maskS[tid] = node_mask[b * NN + tid]; }
  __syncthreads();

  const unsigned short* xrow[2];
#pragma unroll
  for (int mf = 0; mf < 2; ++mf)
    xrow[mf] = xjh + (size_t)(b * NN + jbase + mf * 16 + l15) * H;

  f32x4 acc[2][8];
#pragma unroll
  for (int mf = 0; mf < 2; ++mf)
#pragma unroll
    for (int nt = 0; nt < 8; ++nt)
      acc[mf][nt] = (f32x4){0.f, 0.f, 0.f, 0.f};

  const uint4v* bfrag = (const uint4v*)bw2s;

#pragma unroll
  for (int ks = 0; ks < 8; ++ks) {
    const int kb = ks * 32 + lg * 8;     // f16-elem k offset
    uint4v cc2 = *(const uint4v*)(&cs2[iw][kb >> 1]);
    f16x8 af[2];
#pragma unroll
    for (int mf = 0; mf < 2; ++mf) {
      uint4v xu = *(const uint4v*)(xrow[mf] + kb);
      uint4v au;
#pragma unroll
      for (int p = 0; p < 4; ++p)
        au[p] = pk_relu(pk_add_f16(xu[p], cc2[p]));
      af[mf] = __builtin_bit_cast(f16x8, au);
    }
#pragma unroll
    for (int nt = 0; nt < 8; ++nt) {
      f16x8 bf = __builtin_bit_cast(f16x8, bfrag[(ks * 8 + nt) * 64 + l]);
#pragma unroll
      for (int mf = 0; mf < 2; ++mf)
        acc[mf][nt] = __builtin_amdgcn_mfma_f32_16x16x32_f16(af[mf], bf, acc[mf][nt], 0, 0, 0);
    }
  }

#pragma unroll
  for (int nt = 0; nt < 8; ++nt) {
    const float bias = mb2s[nt * 16 + l15];
    float s = 0.f;
#pragma unroll
    for (int mf = 0; mf < 2; ++mf) {
      const int jb = jbase + mf * 16 + lg * 4;
#pragma unroll
      for (int r = 0; r < 4; ++r)
        s = fmaf(fmaxf(acc[mf][nt][r] + bias, 0.f), maskS[jb + r], s);
    }
    s += __shfl_xor(s, 16);
    s += __shfl_xor(s, 32);
    if (l < 16) waveAgg[w][nt * 16 + l15] = s;
  }
  __syncthreads();
  if (tid < 256) {
    const int ii = tid >> 7, col = tid & 127;
    agg[(size_t)(b * NN + i0 + ii) * D + col] =
        waveAgg[ii * 4][col] + waveAgg[ii * 4 + 1][col] +
        waveAgg[ii * 4 + 2][col] + waveAgg[ii * 4 + 3][col];
  }
}

// ---------------- Kernel 3: update MLP via MFMA + residual + mask --------------
// Block: 16 rows, 256 thr / 4 waves. GEMM1: [ns|agg] f16 (LDS, swizzled) @ w3f
// -> relu+ub1 -> uh f16 LDS. GEMM2: uh @ w4f -> +nodes+ub2, *mask.
__global__ __launch_bounds__(256) void k_upd(
    const float* __restrict__ nodes, const float* __restrict__ agg,
    const unsigned short* __restrict__ w3f, const float* __restrict__ ub1,
    const unsigned short* __restrict__ w4f, const float* __restrict__ ub2,
    const float* __restrict__ node_mask, float* __restrict__ out) {
  const int row0 = blockIdx.x * 16;
  const int tid = threadIdx.x;
  __shared__ unsigned short ah[16 * 256];  // f16 [16][32 groups], swizzled
  __shared__ unsigned short uh[16 * 256];  // f16 u, swizzled
  __shared__ float ns[16][128];
  __shared__ float msk[16];

  {
    const int r = tid >> 4, l16 = tid & 15, d0 = l16 * 8;
    float4 n0 = *(const float4*)(nodes + (size_t)(row0 + r) * D + d0);
    float4 n1 = *(const float4*)(nodes + (size_t)(row0 + r) * D + d0 + 4);
    *(float4*)(&ns[r][d0]) = n0;
    *(float4*)(&ns[r][d0 + 4]) = n1;
    uint4v u;
    u[0] = cvt_pk_f16(n0.x, n0.y); u[1] = cvt_pk_f16(n0.z, n0.w);
    u[2] = cvt_pk_f16(n1.x, n1.y); u[3] = cvt_pk_f16(n1.z, n1.w);
    int g = l16 ^ (r & 7);
    *(uint4v*)(&ah[r * 256 + g * 8]) = u;
    float4 a0 = *(const float4*)(agg + (size_t)(row0 + r) * D + d0);
    float4 a1 = *(const float4*)(agg + (size_t)(row0 + r) * D + d0 + 4);
    u[0] = cvt_pk_f16(a0.x, a0.y); u[1] = cvt_pk_f16(a0.z, a0.w);
    u[2] = cvt_pk_f16(a1.x, a1.y); u[3] = cvt_pk_f16(a1.z, a1.w);
    g = (16 + l16) ^ (r & 7);
    *(uint4v*)(&ah[r * 256 + g * 8]) = u;
    if (tid < 16) msk[tid] = node_mask[row0 + tid];
  }
  __syncthreads();

  const int w = tid >> 6, l = tid & 63;
  const int lg = l >> 4, l15 = l & 15;

  // GEMM1: 16 x 256, K=256
  f32x4 acc[4];
#pragma unroll
  for (int nt = 0; nt < 4; ++nt) acc[nt] = (f32x4){0.f, 0.f, 0.f, 0.f};
#pragma unroll
  for (int ks = 0; ks < 8; ++ks) {
    const int g = (ks * 4 + lg) ^ (l15 & 7);
    f16x8 a = *(const f16x8*)(&ah[l15 * 256 + g * 8]);
#pragma unroll
    for (int nt = 0; nt < 4; ++nt) {
      const int tile = ks * 16 + w * 4 + nt;
      f16x8 bf = *(const f16x8*)(w3f + (size_t)(tile * 64 + l) * 8);
      acc[nt] = __builtin_amdgcn_mfma_f32_16x16x32_f16(a, bf, acc[nt], 0, 0, 0);
    }
  }
  // u = relu(acc + ub1) -> uh (swizzled scalar stores)
#pragma unroll
  for (int nt = 0; nt < 4; ++nt) {
    const int col = w * 64 + nt * 16 + l15;
    const float bias = ub1[col];
#pragma unroll
    for (int r = 0; r < 4; ++r) {
      const int row = lg * 4 + r;
      const int g = (col >> 3) ^ (row & 7);
      uh[row * 256 + g * 8 + (col & 7)] = to_f16u(fmaxf(acc[nt][r] + bias, 0.f));
    }
  }
  __syncthreads();

  // GEMM2: 16 x 128, K=256
  f32x4 acc2[2];
  acc2[0] = (f32x4){0.f, 0.f, 0.f, 0.f};
  acc2[1] = (f32x4){0.f, 0.f, 0.f, 0.f};
#pragma unroll
  for (int ks = 0; ks < 8; ++ks) {
    const int g = (ks * 4 + lg) ^ (l15 & 7);
    f16x8 a = *(const f16x8*)(&uh[l15 * 256 + g * 8]);
#pragma unroll
    for (int nt = 0; nt < 2; ++nt) {
      const int tile = ks * 8 + w * 2 + nt;
      f16x8 bf = *(const f16x8*)(w4f + (size_t)(tile * 64 + l) * 8);
      acc2[nt] = __builtin_amdgcn_mfma_f32_16x16x32_f16(a, bf, acc2[nt], 0, 0, 0);
    }
  }
#pragma unroll
  for (int nt = 0; nt < 2; ++nt) {
    const int col = w * 32 + nt * 16 + l15;
    const float ub2v = ub2[col];
#pragma unroll
    for (int r = 0; r < 4; ++r) {
      const int row = lg * 4 + r;
      out[(size_t)(row0 + row) * D + col] =
          (ns[row][col] + acc2[nt][r] + ub2v) * msk[row];
    }
  }
}

extern "C" void kernel_launch(void* const* d_in, const int* in_sizes, int n_in,
                              void* d_out, int out_size, void* d_ws, size_t ws_size,
                              hipStream_t stream) {
  (void)in_sizes; (void)n_in; (void)out_size; (void)ws_size;
  const float* nodes     = (const float*)d_in[0];
  const float* node_mask = (const float*)d_in[1];
  const float* ln_g      = (const float*)d_in[2];
  const float* ln_b      = (const float*)d_in[3];
  const float* mw1       = (const float*)d_in[4];
  const float* mb1       = (const float*)d_in[5];
  const float* mw2       = (const float*)d_in[6];
  const float* mb2       = (const float*)d_in[7];
  const float* uw1       = (const float*)d_in[8];
  const float* ub1       = (const float*)d_in[9];
  const float* uw2       = (const float*)d_in[10];
  const float* ub2       = (const float*)d_in[11];
  float* out = (float*)d_out;

  char* ws = (char*)d_ws;
  float*          xi_p = (float*)(ws);                               // 4 MB
  unsigned short* xjh  = (unsigned short*)(ws + ((size_t)4 << 20));  // 2 MB
  float*          agg  = (float*)(ws + ((size_t)6 << 20));           // 2 MB
  unsigned short* bw2  = (unsigned short*)(ws + ((size_t)8 << 20));            // 64 KB
  unsigned short* w1f  = (unsigned short*)(ws + ((size_t)8 << 20) + (64 << 10));   // 128 KB
  unsigned short* w3f  = (unsigned short*)(ws + ((size_t)8 << 20) + (192 << 10));  // 128 KB
  unsigned short* w4f  = (unsigned short*)(ws + ((size_t)8 << 20) + (320 << 10));  // 64 KB

  k_repack<<<48, 512, 0, stream>>>(mw1, uw1, uw2, mw2, w1f, w3f, w4f, bw2);
  k_ln_proj<<<dim3(256, 2), 256, 0, stream>>>(nodes, node_mask, ln_g, ln_b, w1f, xi_p, xjh);
  k_msgs<<<dim3(NN / 2, NB), 512, 0, stream>>>(xi_p, xjh, bw2, mb1, mb2, node_mask, agg);
  k_upd<<<256, 256, 0, stream>>>(nodes, agg, w3f, ub1, w4f, ub2, node_mask, out);
}

// Round 19
// 65.159 us; speedup vs baseline: 1.6465x; 1.0839x over previous
//
#include <hip/hip_runtime.h>
#include <hip/hip_bf16.h>

#define D 128
#define H 256
#define NB 32
#define NN 128

typedef __attribute__((ext_vector_type(8))) _Float16 f16x8;
typedef __attribute__((ext_vector_type(4))) float f32x4;
typedef __attribute__((ext_vector_type(16))) float f32x16;
typedef __attribute__((ext_vector_type(4))) unsigned int uint4v;

__device__ __forceinline__ unsigned short to_f16u(float f) {
  _Float16 h = (_Float16)f;
  return __builtin_bit_cast(unsigned short, h);
}

// packed f32x2 -> f16x2: v_cvt_pkrtz_f16_f32 (verified R17)
__device__ __forceinline__ unsigned cvt_pk_f16(float lo, float hi) {
  unsigned d;
  asm("v_cvt_pkrtz_f16_f32 %0, %1, %2" : "=v"(d) : "v"(lo), "v"(hi));
  return d;
}

// packed f16 add (verified R17); v_pk_add_bf16 does NOT exist (R10)
__device__ __forceinline__ unsigned pk_add_f16(unsigned a, unsigned b) {
  unsigned d;
  asm("v_pk_add_f16 %0, %1, %2" : "=v"(d) : "v"(a), "v"(b));
  return d;
}

// packed relu: signed-i16 max with 0 (verified R7-R17)
__device__ __forceinline__ unsigned pk_relu(unsigned x) {
  unsigned d;
  asm("v_pk_max_i16 %0, %1, %2" : "=v"(d) : "v"(x), "v"(0u));
  return d;
}

// ---------------- Kernel 0: repack all weights to f16 MFMA B-fragment order ----
// 16x16x32 frag (w1f/w3f/w4f): lane l, e -> W[ks*32+(l>>4)*8+e][nt*16+(l&15)]
// 32x32x16 frag (bw2, for k_msgs): tile t=(st,ntile): lane l, e ->
//   W[st*16 + (l>>5)*8 + e][ntile*32 + (l&31)]
// Tile map: 0..127 w1f (mw1 K=128 N=512) | 128..255 w3f (uw1 K=256 N=256)
//           256..319 w4f (uw2 K=256 N=128) | 320..383 bw2 (mw2 K=256 N=128, 32x32)
__global__ __launch_bounds__(512) void k_repack(
    const float* __restrict__ mw1, const float* __restrict__ uw1,
    const float* __restrict__ uw2, const float* __restrict__ mw2,
    unsigned short* __restrict__ w1f, unsigned short* __restrict__ w3f,
    unsigned short* __restrict__ w4f, unsigned short* __restrict__ bw2) {
  const int gt = blockIdx.x * 512 + threadIdx.x;
  const int tile = gt >> 6, l = gt & 63;
  const int lg = l >> 4, l15 = l & 15;
  if (tile < 128) {
    const int ks = tile >> 5, ntg = tile & 31;
#pragma unroll
    for (int e = 0; e < 8; ++e) {
      int k = ks * 32 + lg * 8 + e;
      int col = ntg * 16 + l15;
      float v = (col < 256) ? mw1[k * 256 + col] : mw1[(128 + k) * 256 + (col - 256)];
      w1f[(size_t)(tile * 64 + l) * 8 + e] = to_f16u(v);
    }
  } else if (tile < 256) {
    const int t = tile - 128, ks = t >> 4, ntg = t & 15;
#pragma unroll
    for (int e = 0; e < 8; ++e) {
      int k = ks * 32 + lg * 8 + e;
      w3f[(size_t)(t * 64 + l) * 8 + e] = to_f16u(uw1[k * 256 + ntg * 16 + l15]);
    }
  } else if (tile < 320) {
    const int t = tile - 256, ks = t >> 3, ntg = t & 7;
#pragma unroll
    for (int e = 0; e < 8; ++e) {
      int k = ks * 32 + lg * 8 + e;
      w4f[(size_t)(t * 64 + l) * 8 + e] = to_f16u(uw2[k * 128 + ntg * 16 + l15]);
    }
  } else {
    const int t = tile - 320;            // 0..63: st = t>>2, ntile = t&3
    const int st = t >> 2, ntile = t & 3;
    const int lh = l >> 5, l31 = l & 31;
#pragma unroll
    for (int e = 0; e < 8; ++e) {
      int k = st * 16 + lh * 8 + e;
      bw2[(size_t)(t * 64 + l) * 8 + e] = to_f16u(mw2[k * 128 + ntile * 32 + l31]);
    }
  }
}

// ---------------- Kernel 1: LN*mask -> f16 + projection GEMM via MFMA (R18) ----
__global__ __launch_bounds__(256) void k_ln_proj(
    const float* __restrict__ nodes, const float* __restrict__ node_mask,
    const float* __restrict__ ln_g, const float* __restrict__ ln_b,
    const unsigned short* __restrict__ w1f,
    float* __restrict__ xi_p, unsigned short* __restrict__ xjh) {
  const int row0 = blockIdx.x * 16;
  const int half = blockIdx.y;
  const int tid = threadIdx.x;
  __shared__ unsigned short xh[16 * 128];   // f16, 16B-group swizzled

  {
    const int r = tid >> 4, l16 = tid & 15, d0 = l16 * 8;
    float4 v0 = *(const float4*)(nodes + (size_t)(row0 + r) * D + d0);
    float4 v1 = *(const float4*)(nodes + (size_t)(row0 + r) * D + d0 + 4);
    float s1 = v0.x + v0.y + v0.z + v0.w + v1.x + v1.y + v1.z + v1.w;
    float s2 = v0.x * v0.x + v0.y * v0.y + v0.z * v0.z + v0.w * v0.w +
               v1.x * v1.x + v1.y * v1.y + v1.z * v1.z + v1.w * v1.w;
#pragma unroll
    for (int off = 1; off < 16; off <<= 1) {
      s1 += __shfl_xor(s1, off);
      s2 += __shfl_xor(s2, off);
    }
    float mu = s1 * (1.0f / 128.0f);
    float var = s2 * (1.0f / 128.0f) - mu * mu;
    float rsig = rsqrtf(var + 1e-5f);
    float m = node_mask[row0 + r];
    float4 g0 = *(const float4*)(ln_g + d0), g1 = *(const float4*)(ln_g + d0 + 4);
    float4 b0 = *(const float4*)(ln_b + d0), b1 = *(const float4*)(ln_b + d0 + 4);
    float x0 = ((v0.x - mu) * rsig * g0.x + b0.x) * m;
    float x1 = ((v0.y - mu) * rsig * g0.y + b0.y) * m;
    float x2 = ((v0.z - mu) * rsig * g0.z + b0.z) * m;
    float x3 = ((v0.w - mu) * rsig * g0.w + b0.w) * m;
    float x4 = ((v1.x - mu) * rsig * g1.x + b1.x) * m;
    float x5 = ((v1.y - mu) * rsig * g1.y + b1.y) * m;
    float x6 = ((v1.z - mu) * rsig * g1.z + b1.z) * m;
    float x7 = ((v1.w - mu) * rsig * g1.w + b1.w) * m;
    uint4v u;
    u[0] = cvt_pk_f16(x0, x1); u[1] = cvt_pk_f16(x2, x3);
    u[2] = cvt_pk_f16(x4, x5); u[3] = cvt_pk_f16(x6, x7);
    const int g = l16 ^ (r & 7);          // swizzled 16B-group index
    *(uint4v*)(&xh[r * 128 + g * 8]) = u;
  }
  __syncthreads();

  const int w = tid >> 6, l = tid & 63;
  const int lg = l >> 4, l15 = l & 15;
  f32x4 acc[4];
#pragma unroll
  for (int nt = 0; nt < 4; ++nt) acc[nt] = (f32x4){0.f, 0.f, 0.f, 0.f};

#pragma unroll
  for (int ks = 0; ks < 4; ++ks) {
    const int g = (ks * 4 + lg) ^ (l15 & 7);
    f16x8 a = *(const f16x8*)(&xh[l15 * 128 + g * 8]);
#pragma unroll
    for (int nt = 0; nt < 4; ++nt) {
      const int tile = ks * 32 + half * 16 + w * 4 + nt;
      f16x8 bf = *(const f16x8*)(w1f + (size_t)(tile * 64 + l) * 8);
      acc[nt] = __builtin_amdgcn_mfma_f32_16x16x32_f16(a, bf, acc[nt], 0, 0, 0);
    }
  }

  if (half == 0) {
#pragma unroll
    for (int nt = 0; nt < 4; ++nt)
#pragma unroll
      for (int r = 0; r < 4; ++r)
        xi_p[(size_t)(row0 + lg * 4 + r) * H + w * 64 + nt * 16 + l15] = acc[nt][r];
  } else {
#pragma unroll
    for (int nt = 0; nt < 4; ++nt)
#pragma unroll
      for (int r = 0; r < 4; ++r)
        xjh[(size_t)(row0 + lg * 4 + r) * H + w * 64 + nt * 16 + l15] = to_f16u(acc[nt][r]);
  }
}

// ---------------- Kernel 2: msgs GEMM via 32x32x16 MFMA + mask + sum -> agg ----
// R19: same tile (TM=32, NT=128) but mfma_f32_32x32x16_f16 (2495 TF vs 2075,
// m119). Wave: 1 row-tile (32 j) x 4 col-tiles (32 n each); acc = 4 x f32x16
// = 64 AGPRs (same), but arch regs drop (~1 xrow ptr, 1 af frag, no mf loop)
// -> headroom under the 128 cap for load pipelining R8/R17 lacked.
// A/B use the SAME assumed lane->k map (k = st*16 + (l>>5)*8 + e), so any
// bijective k-permutation error cancels (R0 argument). C-layout m74/m101
// verified: col = l&31, row = (reg&3) + 8*(reg>>2) + 4*(l>>5).
// Lessons kept: no bigger TM (R4/R7/R9/R11), B in LDS (R12), no dup A-build
// (R15). Spill tripwire: WRITE_SIZE ~2MB.
__global__ __launch_bounds__(512, 4) void k_msgs(
    const float* __restrict__ xi_p, const unsigned short* __restrict__ xjh,
    const unsigned short* __restrict__ bw2g, const float* __restrict__ mb1,
    const float* __restrict__ mb2, const float* __restrict__ node_mask,
    float* __restrict__ agg) {
  const int b = blockIdx.y;
  const int i0 = blockIdx.x * 2;
  const int tid = threadIdx.x;           // 0..511
  const int w = tid >> 6, l = tid & 63;  // 8 waves
  const int iw = w >> 2;                 // 0..1: which i
  const int jbase = (w & 3) * 32;        // which 32-row j-slab
  const int l31 = l & 31, lh = l >> 5;   // row-in-tile, k-half

  __shared__ unsigned short bw2s[32768]; // 64 KB B fragments (64 tiles x 1KB)
  __shared__ unsigned cs2[2][128];       // f16-pair (xi_p + mb1), per i
  __shared__ float mb2s[128], maskS[128];
  __shared__ float waveAgg[8][128];

  {
    const uint4v* src = (const uint4v*)bw2g;
    uint4v* dst = (uint4v*)bw2s;
#pragma unroll
    for (int c = 0; c < 8; ++c) dst[c * 512 + tid] = src[c * 512 + tid];
  }
  if (tid < 256) {
    int ii = tid >> 7, p = tid & 127;
    float2 xi2 = *(const float2*)(xi_p + (size_t)(b * NN + i0 + ii) * H + 2 * p);
    float2 mbv = *(const float2*)(mb1 + 2 * p);
    cs2[ii][p] = cvt_pk_f16(xi2.x + mbv.x, xi2.y + mbv.y);
  }
  if (tid < 128) { mb2s[tid] = mb2[tid]; maskS[tid] = node_mask[b * NN + tid]; }
  __syncthreads();

  // A row for this lane: j = jbase + l31; k-chunk = st*16 + lh*8 .. +8
  const unsigned short* xrow = xjh + (size_t)(b * NN + jbase + l31) * H;

  f32x16 acc[4];
#pragma unroll
  for (int nt = 0; nt < 4; ++nt)
#pragma unroll
    for (int r = 0; r < 16; ++r) acc[nt][r] = 0.f;

  const uint4v* bfrag = (const uint4v*)bw2s;

#pragma unroll
  for (int st = 0; st < 16; ++st) {
    const int kb = st * 16 + lh * 8;     // f16-elem k offset
    uint4v cc2 = *(const uint4v*)(&cs2[iw][kb >> 1]);
    uint4v xu = *(const uint4v*)(xrow + kb);
    uint4v au;
#pragma unroll
    for (int p = 0; p < 4; ++p)
      au[p] = pk_relu(pk_add_f16(xu[p], cc2[p]));
    f16x8 af = __builtin_bit_cast(f16x8, au);
#pragma unroll
    for (int nt = 0; nt < 4; ++nt) {
      f16x8 bf = __builtin_bit_cast(f16x8, bfrag[(st * 4 + nt) * 64 + l]);
      acc[nt] = __builtin_amdgcn_mfma_f32_32x32x16_f16(af, bf, acc[nt], 0, 0, 0);
    }
  }

  // Epilogue: relu(acc+mb2)*mask_j, column-sum over the tile's 32 j rows.
  // C map: col = nt*32 + l31, row j = jbase + 4*lh + (reg&3) + 8*(reg>>2).
#pragma unroll
  for (int nt = 0; nt < 4; ++nt) {
    const float bias = mb2s[nt * 32 + l31];
    float s = 0.f;
#pragma unroll
    for (int reg = 0; reg < 16; ++reg) {
      const int j = jbase + 4 * lh + (reg & 3) + 8 * (reg >> 2);
      s = fmaf(fmaxf(acc[nt][reg] + bias, 0.f), maskS[j], s);
    }
    s += __shfl_xor(s, 32);
    if (l < 32) waveAgg[w][nt * 32 + l31] = s;
  }
  __syncthreads();
  if (tid < 256) {
    const int ii = tid >> 7, col = tid & 127;  // 2 i's x 128 cols
    agg[(size_t)(b * NN + i0 + ii) * D + col] =
        waveAgg[ii * 4][col] + waveAgg[ii * 4 + 1][col] +
        waveAgg[ii * 4 + 2][col] + waveAgg[ii * 4 + 3][col];
  }
}

// ---------------- Kernel 3: update MLP via MFMA + residual + mask (R18) --------
__global__ __launch_bounds__(256) void k_upd(
    const float* __restrict__ nodes, const float* __restrict__ agg,
    const unsigned short* __restrict__ w3f, const float* __restrict__ ub1,
    const unsigned short* __restrict__ w4f, const float* __restrict__ ub2,
    const float* __restrict__ node_mask, float* __restrict__ out) {
  const int row0 = blockIdx.x * 16;
  const int tid = threadIdx.x;
  __shared__ unsigned short ah[16 * 256];  // f16 [16][32 groups], swizzled
  __shared__ unsigned short uh[16 * 256];  // f16 u, swizzled
  __shared__ float ns[16][128];
  __shared__ float msk[16];

  {
    const int r = tid >> 4, l16 = tid & 15, d0 = l16 * 8;
    float4 n0 = *(const float4*)(nodes + (size_t)(row0 + r) * D + d0);
    float4 n1 = *(const float4*)(nodes + (size_t)(row0 + r) * D + d0 + 4);
    *(float4*)(&ns[r][d0]) = n0;
    *(float4*)(&ns[r][d0 + 4]) = n1;
    uint4v u;
    u[0] = cvt_pk_f16(n0.x, n0.y); u[1] = cvt_pk_f16(n0.z, n0.w);
    u[2] = cvt_pk_f16(n1.x, n1.y); u[3] = cvt_pk_f16(n1.z, n1.w);
    int g = l16 ^ (r & 7);
    *(uint4v*)(&ah[r * 256 + g * 8]) = u;
    float4 a0 = *(const float4*)(agg + (size_t)(row0 + r) * D + d0);
    float4 a1 = *(const float4*)(agg + (size_t)(row0 + r) * D + d0 + 4);
    u[0] = cvt_pk_f16(a0.x, a0.y); u[1] = cvt_pk_f16(a0.z, a0.w);
    u[2] = cvt_pk_f16(a1.x, a1.y); u[3] = cvt_pk_f16(a1.z, a1.w);
    g = (16 + l16) ^ (r & 7);
    *(uint4v*)(&ah[r * 256 + g * 8]) = u;
    if (tid < 16) msk[tid] = node_mask[row0 + tid];
  }
  __syncthreads();

  const int w = tid >> 6, l = tid & 63;
  const int lg = l >> 4, l15 = l & 15;

  // GEMM1: 16 x 256, K=256
  f32x4 acc[4];
#pragma unroll
  for (int nt = 0; nt < 4; ++nt) acc[nt] = (f32x4){0.f, 0.f, 0.f, 0.f};
#pragma unroll
  for (int ks = 0; ks < 8; ++ks) {
    const int g = (ks * 4 + lg) ^ (l15 & 7);
    f16x8 a = *(const f16x8*)(&ah[l15 * 256 + g * 8]);
#pragma unroll
    for (int nt = 0; nt < 4; ++nt) {
      const int tile = ks * 16 + w * 4 + nt;
      f16x8 bf = *(const f16x8*)(w3f + (size_t)(tile * 64 + l) * 8);
      acc[nt] = __builtin_amdgcn_mfma_f32_16x16x32_f16(a, bf, acc[nt], 0, 0, 0);
    }
  }
  // u = relu(acc + ub1) -> uh (swizzled scalar stores)
#pragma unroll
  for (int nt = 0; nt < 4; ++nt) {
    const int col = w * 64 + nt * 16 + l15;
    const float bias = ub1[col];
#pragma unroll
    for (int r = 0; r < 4; ++r) {
      const int row = lg * 4 + r;
      const int g = (col >> 3) ^ (row & 7);
      uh[row * 256 + g * 8 + (col & 7)] = to_f16u(fmaxf(acc[nt][r] + bias, 0.f));
    }
  }
  __syncthreads();

  // GEMM2: 16 x 128, K=256
  f32x4 acc2[2];
  acc2[0] = (f32x4){0.f, 0.f, 0.f, 0.f};
  acc2[1] = (f32x4){0.f, 0.f, 0.f, 0.f};
#pragma unroll
  for (int ks = 0; ks < 8; ++ks) {
    const int g = (ks * 4 + lg) ^ (l15 & 7);
    f16x8 a = *(const f16x8*)(&uh[l15 * 256 + g * 8]);
#pragma unroll
    for (int nt = 0; nt < 2; ++nt) {
      const int tile = ks * 8 + w * 2 + nt;
      f16x8 bf = *(const f16x8*)(w4f + (size_t)(tile * 64 + l) * 8);
      acc2[nt] = __builtin_amdgcn_mfma_f32_16x16x32_f16(a, bf, acc2[nt], 0, 0, 0);
    }
  }
#pragma unroll
  for (int nt = 0; nt < 2; ++nt) {
    const int col = w * 32 + nt * 16 + l15;
    const float ub2v = ub2[col];
#pragma unroll
    for (int r = 0; r < 4; ++r) {
      const int row = lg * 4 + r;
      out[(size_t)(row0 + row) * D + col] =
          (ns[row][col] + acc2[nt][r] + ub2v) * msk[row];
    }
  }
}

extern "C" void kernel_launch(void* const* d_in, const int* in_sizes, int n_in,
                              void* d_out, int out_size, void* d_ws, size_t ws_size,
                              hipStream_t stream) {
  (void)in_sizes; (void)n_in; (void)out_size; (void)ws_size;
  const float* nodes     = (const float*)d_in[0];
  const float* node_mask = (const float*)d_in[1];
  const float* ln_g      = (const float*)d_in[2];
  const float* ln_b      = (const float*)d_in[3];
  const float* mw1       = (const float*)d_in[4];
  const float* mb1       = (const float*)d_in[5];
  const float* mw2       = (const float*)d_in[6];
  const float* mb2       = (const float*)d_in[7];
  const float* uw1       = (const float*)d_in[8];
  const float* ub1       = (const float*)d_in[9];
  const float* uw2       = (const float*)d_in[10];
  const float* ub2       = (const float*)d_in[11];
  float* out = (float*)d_out;

  char* ws = (char*)d_ws;
  float*          xi_p = (float*)(ws);                               // 4 MB
  unsigned short* xjh  = (unsigned short*)(ws + ((size_t)4 << 20));  // 2 MB
  float*          agg  = (float*)(ws + ((size_t)6 << 20));           // 2 MB
  unsigned short* bw2  = (unsigned short*)(ws + ((size_t)8 << 20));            // 64 KB
  unsigned short* w1f  = (unsigned short*)(ws + ((size_t)8 << 20) + (64 << 10));   // 128 KB
  unsigned short* w3f  = (unsigned short*)(ws + ((size_t)8 << 20) + (192 << 10));  // 128 KB
  unsigned short* w4f  = (unsigned short*)(ws + ((size_t)8 << 20) + (320 << 10));  // 64 KB

  k_repack<<<48, 512, 0, stream>>>(mw1, uw1, uw2, mw2, w1f, w3f, w4f, bw2);
  k_ln_proj<<<dim3(256, 2), 256, 0, stream>>>(nodes, node_mask, ln_g, ln_b, w1f, xi_p, xjh);
  k_msgs<<<dim3(NN / 2, NB), 512, 0, stream>>>(xi_p, xjh, bw2, mb1, mb2, node_mask, agg);
  k_upd<<<256, 256, 0, stream>>>(nodes, agg, w3f, ub1, w4f, ub2, node_mask, out);
}